// Round 11
// baseline (21149.623 us; speedup 1.0000x reference)
//
#include <hip/hip_runtime.h>
#include <stdint.h>

#define B_SZ   2048
#define T_ENC  168
#define TEMPD  128
#define HID    1024
#define M_DEC  48
#define NBLK   512

typedef _Float16 f16;
typedef _Float16 half8 __attribute__((ext_vector_type(8)));
typedef float    f32x4 __attribute__((ext_vector_type(4)));

__device__ __forceinline__ float sigf(float x)   { return 1.0f / (1.0f + __expf(-x)); }
__device__ __forceinline__ float tanhf_(float x) { return 2.0f / (1.0f + __expf(-2.0f * x)) - 1.0f; }

// Direct global->LDS, 16B per lane. AUX: 0 = cached; 17 = sc0|sc1 coherent path.
template <int AUX>
__device__ __forceinline__ void gld16(const void* g, void* l) {
    __builtin_amdgcn_global_load_lds(
        (const __attribute__((address_space(1))) void*)g,
        (__attribute__((address_space(3))) void*)l, 16, 0, AUX);
}

// 2-byte store with sc0 sc1: write-through to coherent point.
__device__ __forceinline__ void store_h16(f16* p, f16 v) {
    union { f16 h; unsigned short u; } cv; cv.h = v;
    unsigned v32 = cv.u;
    asm volatile("global_store_short %0, %1, off sc0 sc1" :: "v"(p), "v"(v32) : "memory");
}

// ---------------------------------------------------------------------------
// prep_xseq: temp_seq [B][T][128] fp32 -> xseq [T][B][128] f16
// ---------------------------------------------------------------------------
__global__ void prep_xseq(const float* __restrict__ temp_seq, f16* __restrict__ xseq)
{
    size_t i4 = ((size_t)blockIdx.x * blockDim.x + threadIdx.x) * 4;
    size_t b  = i4 / (T_ENC * TEMPD);
    size_t r  = i4 - b * (T_ENC * TEMPD);
    size_t t  = r >> 7;
    size_t d  = r & 127;
    float4 v = *(const float4*)(temp_seq + i4);
    f16* o = xseq + ((t * B_SZ) + b) * TEMPD + d;
    o[0] = (f16)v.x; o[1] = (f16)v.y; o[2] = (f16)v.z; o[3] = (f16)v.w;
}

// ---------------------------------------------------------------------------
// prep_misc: merged f16 weights [4H][128+1024], fcW f16, biases, wlast
// ---------------------------------------------------------------------------
__global__ void prep_misc(
    const float* __restrict__ encWih, const float* __restrict__ encWhh,
    const float* __restrict__ decWih, const float* __restrict__ decWhh,
    const float* __restrict__ encbih, const float* __restrict__ encbhh,
    const float* __restrict__ decbih, const float* __restrict__ decbhh,
    const float* __restrict__ fcW,
    f16* __restrict__ Wenc, f16* __restrict__ Wdec0, f16* __restrict__ fcWh,
    float* __restrict__ enc_b, float* __restrict__ dec_b, float* __restrict__ wlast)
{
    const int NW = 4 * HID * (TEMPD + HID);
    for (int idx = blockIdx.x * blockDim.x + threadIdx.x; idx < NW;
         idx += gridDim.x * blockDim.x) {
        int j = idx / (TEMPD + HID);
        int k = idx - j * (TEMPD + HID);
        Wenc[idx]  = (f16)(k < TEMPD ? encWih[j * TEMPD + k]
                                     : encWhh[(size_t)j * HID + (k - TEMPD)]);
        Wdec0[idx] = (f16)(k < TEMPD ? decWih[j * (TEMPD + 1) + k]
                                     : decWhh[(size_t)j * HID + (k - TEMPD)]);
        if (idx < TEMPD * HID) fcWh[idx] = (f16)fcW[idx];
        if (idx < 4 * HID) {
            enc_b[idx] = encbih[idx] + encbhh[idx];
            dec_b[idx] = decbih[idx] + decbhh[idx];
            wlast[idx] = decWih[idx * (TEMPD + 1) + TEMPD];
        }
    }
}

// ---------------------------------------------------------------------------
// prep_fold: WdecF = decWhh + decWih_x @ fcW ; biasF = decb + decWih_x @ fcb
// ---------------------------------------------------------------------------
__global__ __launch_bounds__(256)
void prep_fold(
    const float* __restrict__ decWih, const float* __restrict__ decWhh,
    const float* __restrict__ decbih, const float* __restrict__ decbhh,
    const float* __restrict__ fcW,    const float* __restrict__ fcb,
    f16* __restrict__ WdecF, float* __restrict__ biasF)
{
    __shared__ float wih[16][TEMPD];
    __shared__ float fcbL[TEMPD];
    const int tid = threadIdx.x;
    const int j0  = blockIdx.x * 16;
    for (int i = tid; i < 16 * TEMPD; i += 256) {
        int r = i >> 7, p = i & 127;
        wih[r][p] = decWih[(size_t)(j0 + r) * (TEMPD + 1) + p];
    }
    if (tid < TEMPD) fcbL[tid] = fcb[tid];
    __syncthreads();
    for (int kk = 0; kk < 4; ++kk) {
        int k = kk * 256 + tid;
        float acc[16];
        #pragma unroll
        for (int r = 0; r < 16; ++r) acc[r] = decWhh[(size_t)(j0 + r) * HID + k];
        for (int p = 0; p < TEMPD; ++p) {
            float w = fcW[(size_t)p * HID + k];
            #pragma unroll
            for (int r = 0; r < 16; ++r) acc[r] += wih[r][p] * w;
        }
        #pragma unroll
        for (int r = 0; r < 16; ++r) WdecF[(size_t)(j0 + r) * HID + k] = (f16)acc[r];
    }
    if (tid < 16) {
        float b = decbih[j0 + tid] + decbhh[j0 + tid];
        for (int p = 0; p < TEMPD; ++p) b += wih[tid][p] * fcbL[p];
        biasF[j0 + tid] = b;
    }
}

// ---------------------------------------------------------------------------
// prep_tileW: merged W [4096][WS] -> fragment-ordered tiles.
// Frag flat index F = bn*NKC*16 + kc*16 + s*8 + g*2 + wc; half8 addr = F*64+lane.
// ---------------------------------------------------------------------------
__global__ void prep_tileW(const f16* __restrict__ Wsrc, f16* __restrict__ Wt,
                           int NKC, int WS)
{
    int idx = blockIdx.x * blockDim.x + threadIdx.x;
    int total = 32 * NKC * 16 * 64;
    if (idx >= total) return;
    int lane = idx & 63;
    int f    = idx >> 6;
    int wc   = f & 1;
    int g    = (f >> 1) & 3;
    int s    = (f >> 3) & 1;
    int kc   = (f >> 4) % NKC;
    int bn   = (f >> 4) / NKC;
    int row  = g * HID + bn * 32 + wc * 16 + (lane & 15);
    int k0   = kc * 64 + s * 32 + (lane >> 4) * 8;
    *(half8*)(Wt + (size_t)idx * 8) = *(const half8*)(Wsrc + (size_t)row * WS + k0);
}

// ---------------------------------------------------------------------------
// Persistent kernel, 4-slot / 3-ahead pipeline for A (LDS) and W (regs).
// Per kc: vmcnt(24) -> s_barrier -> issue A(kc+3)+W(kc+3) -> compute(kc).
// Counted vmcnt: 12 loads/iter (4 gld16 A + 8 W), 3 iters in flight = 36;
// vmcnt(24) drains exactly the oldest group (A(kc), W(kc)).
// ---------------------------------------------------------------------------
struct PK {
    const f16* xseq; f16* hA; f16* hB; float* c;
    const f16* WencT; const f16* Wdec0T; const f16* WdecFT;
    const float* enc_b; const float* dec_b; const float* biasF;
    const float* wlast; const float* speeds;
    f16* hist; const f16* fcWh; const float* fcb; float* out;
    unsigned* bar;
};

__device__ __forceinline__ void gridbar(unsigned* bar, int xcd, unsigned target)
{
    __syncthreads();   // drains vmcnt(0) per wave -> h sc-stores visible
    if (threadIdx.x == 0) {
        unsigned a = __hip_atomic_fetch_add(&bar[xcd * 32], 1u,
                        __ATOMIC_RELAXED, __HIP_MEMORY_SCOPE_AGENT);
        if (((a + 1) & 63) == 0) {
            unsigned b = __hip_atomic_fetch_add(&bar[256], 1u,
                            __ATOMIC_RELAXED, __HIP_MEMORY_SCOPE_AGENT);
            if (((b + 1) & 7) == 0)
                __hip_atomic_store(&bar[288], target,
                    __ATOMIC_RELAXED, __HIP_MEMORY_SCOPE_AGENT);
        }
        long spin = 0;
        while (__hip_atomic_load(&bar[288], __ATOMIC_RELAXED,
                                 __HIP_MEMORY_SCOPE_AGENT) < target) {
            __builtin_amdgcn_s_sleep(1);
            if (++spin > 400000) break;            // fail loud, never hang
        }
        asm volatile("" ::: "memory");
    }
    __syncthreads();
}

template <int NKC, int FULLK, int DEC>
__device__ __forceinline__ void lstm_step_body(
    const f16* __restrict__ xsrc, const f16* __restrict__ hin,
    f16* __restrict__ hout, float* __restrict__ c,
    const f16* __restrict__ Wt, const float* __restrict__ bias,
    const float* __restrict__ wlast, const float* __restrict__ speeds,
    int m, int bm, int bn, half8* smem)
{
    const int tid  = threadIdx.x;
    const int lane = tid & 63;
    const int wid  = tid >> 6;
    const int wr   = wid >> 1;
    const int wc   = wid & 1;

    const half8* wtb = (const half8*)Wt + (size_t)bn * NKC * 16 * 64 + wc * 64 + lane;

    f32x4 acc[4][4];
    #pragma unroll
    for (int g = 0; g < 4; ++g)
        #pragma unroll
        for (int mr = 0; mr < 4; ++mr)
            acc[g][mr] = (f32x4){0.f, 0.f, 0.f, 0.f};

    half8 wf[4][8];   // 4-deep W register ring (static indices via full unroll)

    auto stageA = [&](int slot, int kc) {
        if (FULLK && kc < 2) {
            #pragma unroll
            for (int it = 0; it < 4; ++it) {
                int pc = wid * 256 + it * 64 + lane;
                int row = pc >> 3, s = pc & 7;
                gld16<0>(xsrc + (size_t)(bm * 128 + row) * TEMPD + kc * 64 + ((s ^ (row & 7)) << 3),
                         &smem[slot * 1024 + wid * 256 + it * 64]);
            }
        } else {
            const int k0 = kc * 64 - (FULLK ? TEMPD : 0);
            #pragma unroll
            for (int it = 0; it < 4; ++it) {
                int pc = wid * 256 + it * 64 + lane;
                int row = pc >> 3, s = pc & 7;
                gld16<17>(hin + (size_t)(bm * 128 + row) * HID + k0 + ((s ^ (row & 7)) << 3),
                          &smem[slot * 1024 + wid * 256 + it * 64]);
            }
        }
    };

    // ---- prologue: stages 0,1,2 in flight (36 outstanding loads/wave) ----
    stageA(0, 0);
    { const half8* pw = wtb; 
      #pragma unroll
      for (int f = 0; f < 8; ++f) wf[0][f] = pw[f * 128]; }
    stageA(1, 1);
    { const half8* pw = wtb + (size_t)1 * (16 * 64);
      #pragma unroll
      for (int f = 0; f < 8; ++f) wf[1][f] = pw[f * 128]; }
    stageA(2, 2);
    { const half8* pw = wtb + (size_t)2 * (16 * 64);
      #pragma unroll
      for (int f = 0; f < 8; ++f) wf[2][f] = pw[f * 128]; }

    #pragma unroll
    for (int kc = 0; kc < NKC; ++kc) {
        asm volatile("s_waitcnt vmcnt(24)" ::: "memory");   // A(kc),W(kc) done
        __builtin_amdgcn_sched_barrier(0);
        __builtin_amdgcn_s_barrier();                        // A(kc) visible block-wide
        __builtin_amdgcn_sched_barrier(0);
        const int pf = (kc + 3 < NKC) ? kc + 3 : NKC - 1;    // clamped tail (dummy)
        stageA((kc + 3) & 3, pf);
        __builtin_amdgcn_sched_barrier(0);
        { const half8* pw = wtb + (size_t)pf * (16 * 64);
          #pragma unroll
          for (int f = 0; f < 8; ++f) wf[(kc + 3) & 3][f] = pw[f * 128]; }
        __builtin_amdgcn_sched_barrier(0);
        // ---- compute kc from slot kc&3, wf[kc&3] ----
        #pragma unroll
        for (int s = 0; s < 2; ++s) {
            const int ks = s * 4 + (lane >> 4);
            half8 af[4];
            #pragma unroll
            for (int mr = 0; mr < 4; ++mr) {
                int row = wr * 64 + mr * 16 + (lane & 15);
                af[mr] = smem[(kc & 3) * 1024 + row * 8 + (ks ^ (row & 7))];
            }
            __builtin_amdgcn_s_setprio(1);
            #pragma unroll
            for (int g = 0; g < 4; ++g)
                #pragma unroll
                for (int mr = 0; mr < 4; ++mr)
                    acc[g][mr] = __builtin_amdgcn_mfma_f32_16x16x32_f16(
                        af[mr], wf[kc & 3][s * 4 + g], acc[g][mr], 0, 0, 0);
            __builtin_amdgcn_s_setprio(0);
        }
    }

    // ---- epilogue: LSTM pointwise; h stored via sc0sc1, c cached ----
    const int col_g = bn * 32 + wc * 16 + (lane & 15);
    const float bi  = bias[col_g];
    const float bf_ = bias[HID + col_g];
    const float bg  = bias[2 * HID + col_g];
    const float bo  = bias[3 * HID + col_g];
    float wli = 0.f, wlf = 0.f, wlg = 0.f, wlo = 0.f;
    if (DEC) {
        wli = wlast[col_g];
        wlf = wlast[HID + col_g];
        wlg = wlast[2 * HID + col_g];
        wlo = wlast[3 * HID + col_g];
    }
    #pragma unroll
    for (int mr = 0; mr < 4; ++mr) {
        #pragma unroll
        for (int q = 0; q < 4; ++q) {
            int row_g = bm * 128 + wr * 64 + mr * 16 + (lane >> 4) * 4 + q;
            float pi = acc[0][mr][q] + bi;
            float pf2 = acc[1][mr][q] + bf_;
            float pg = acc[2][mr][q] + bg;
            float po = acc[3][mr][q] + bo;
            if (DEC) {
                float sp = speeds[(size_t)row_g * M_DEC + m];
                pi += sp * wli; pf2 += sp * wlf; pg += sp * wlg; po += sp * wlo;
            }
            float ii = sigf(pi), ff = sigf(pf2), gg = tanhf_(pg), oo = sigf(po);
            size_t idx = (size_t)row_g * HID + col_g;
            float cn = ff * c[idx] + ii * gg;
            c[idx] = cn;
            store_h16(hout + idx, (f16)(oo * tanhf_(cn)));
        }
    }
}

__global__ __launch_bounds__(256, 2)
void persist(PK p)
{
    __shared__ half8 smem[4096];   // 64 KB: 4 x 16 KB A slots; fc reuses [0,1280)

    const size_t SLOT = (size_t)B_SZ * HID;
    const int tid  = threadIdx.x;
    const int lane = tid & 63;
    const int wid  = tid >> 6;
    const int wr   = wid >> 1;
    const int wc   = wid & 1;
    const int id   = blockIdx.x;
    const int xcd  = id & 7;
    const int swzb = xcd * 64 + (id >> 3);        // bijective XCD swizzle
    const int bn   = swzb >> 4;
    const int bm   = swzb & 15;

    for (int step = 0; step < T_ENC + M_DEC; ++step) {
        const int m = step - T_ENC;
        if (step < T_ENC) {
            const f16* xsrc = p.xseq + (size_t)step * (B_SZ * TEMPD);
            const f16* hin  = (step & 1) ? p.hB : p.hA;
            f16* hout       = (step & 1) ? p.hA : p.hB;
            lstm_step_body<18, 1, 0>(xsrc, hin, hout, p.c, p.WencT, p.enc_b,
                                     nullptr, nullptr, 0, bm, bn, smem);
        } else if (m == 0) {
            const f16* xsrc = p.xseq + (size_t)(T_ENC - 1) * (B_SZ * TEMPD);
            lstm_step_body<18, 1, 1>(xsrc, p.hA, p.hist, p.c, p.Wdec0T, p.dec_b,
                                     p.wlast, p.speeds, 0, bm, bn, smem);
        } else {
            const f16* hin = p.hist + (size_t)(m - 1) * SLOT;
            f16* hout      = p.hist + (size_t)m * SLOT;
            lstm_step_body<16, 0, 1>(nullptr, hin, hout, p.c, p.WdecFT, p.biasF,
                                     p.wlast, p.speeds, m, bm, bn, smem);
        }
        gridbar(p.bar, xcd, (unsigned)(step + 1));
    }

    // ---- fc phase: preds[slot] = hist[slot] @ fcW^T + fcb -> d_out ----
    for (int tile = id; tile < M_DEC * 64; tile += NBLK) {
        const int slot = tile >> 6;
        const int b0   = (tile & 63) * 32;
        const f16* hrow = p.hist + (size_t)slot * SLOT + (size_t)b0 * HID;

        f32x4 facc[4];
        #pragma unroll
        for (int nr = 0; nr < 4; ++nr) facc[nr] = (f32x4){0.f, 0.f, 0.f, 0.f};

        for (int kc = 0; kc < HID / 64; ++kc) {
            const int k0 = kc * 64;
            {
                int row = tid >> 3, s = tid & 7;
                gld16<0>(hrow + (size_t)row * HID + k0 + ((s ^ (row & 7)) << 3), &smem[wid * 64]);
            }
            #pragma unroll
            for (int it = 0; it < 4; ++it) {
                int pc = wid * 256 + it * 64 + lane;
                int row = pc >> 3, s = pc & 7;
                gld16<0>(p.fcWh + (size_t)row * HID + k0 + ((s ^ (row & 7)) << 3),
                         &smem[256 + wid * 256 + it * 64]);
            }
            __syncthreads();
            #pragma unroll
            for (int s2 = 0; s2 < 2; ++s2) {
                int arow = wr * 16 + (lane & 15);
                int ks = s2 * 4 + (lane >> 4);
                half8 a = smem[arow * 8 + (ks ^ (arow & 7))];
                #pragma unroll
                for (int nr = 0; nr < 4; ++nr) {
                    int brow = wc * 64 + nr * 16 + (lane & 15);
                    half8 bfr = smem[256 + brow * 8 + (ks ^ (brow & 7))];
                    facc[nr] = __builtin_amdgcn_mfma_f32_16x16x32_f16(a, bfr, facc[nr], 0, 0, 0);
                }
            }
            __syncthreads();
        }
        #pragma unroll
        for (int nr = 0; nr < 4; ++nr)
            #pragma unroll
            for (int q = 0; q < 4; ++q) {
                int rloc = wr * 16 + (lane >> 4) * 4 + q;
                int col  = wc * 64 + nr * 16 + (lane & 15);
                p.out[(size_t)(b0 + rloc) * (M_DEC * TEMPD) + (size_t)slot * TEMPD + col]
                    = facc[nr][q] + p.fcb[col];
            }
    }
}

// ---------------------------------------------------------------------------
extern "C" void kernel_launch(void* const* d_in, const int* in_sizes, int n_in,
                              void* d_out, int out_size, void* d_ws, size_t ws_size,
                              hipStream_t stream)
{
    (void)in_sizes; (void)n_in; (void)out_size; (void)ws_size;
    const float* temp_seq   = (const float*)d_in[0];
    const float* avg_speeds = (const float*)d_in[1];
    const float* enc_Wih    = (const float*)d_in[2];
    const float* enc_Whh    = (const float*)d_in[3];
    const float* enc_bih    = (const float*)d_in[4];
    const float* enc_bhh    = (const float*)d_in[5];
    const float* dec_Wih    = (const float*)d_in[6];
    const float* dec_Whh    = (const float*)d_in[7];
    const float* dec_bih    = (const float*)d_in[8];
    const float* dec_bhh    = (const float*)d_in[9];
    const float* fc_W       = (const float*)d_in[10];
    const float* fc_b       = (const float*)d_in[11];
    float* out = (float*)d_out;

    char* ws = (char*)d_ws;
    size_t off = 0;
    auto alloc = [&](size_t bytes) -> void* {
        void* p = ws + off;
        off += (bytes + 255) & ~(size_t)255;
        return p;
    };
    const size_t SLOT = (size_t)B_SZ * HID;
    f16*   Wenc   = (f16*)alloc((size_t)4 * HID * (TEMPD + HID) * 2);
    f16*   Wdec0  = (f16*)alloc((size_t)4 * HID * (TEMPD + HID) * 2);
    f16*   WdecF  = (f16*)alloc((size_t)4 * HID * HID * 2);
    f16*   WencT  = (f16*)alloc((size_t)32 * 18 * 16 * 64 * 8 * 2);
    f16*   Wdec0T = (f16*)alloc((size_t)32 * 18 * 16 * 64 * 8 * 2);
    f16*   WdecFT = (f16*)alloc((size_t)32 * 16 * 16 * 64 * 8 * 2);
    f16*   fcWh   = (f16*)alloc((size_t)TEMPD * HID * 2);
    float* enc_b  = (float*)alloc((size_t)4 * HID * 4);
    float* dec_b  = (float*)alloc((size_t)4 * HID * 4);
    float* biasF  = (float*)alloc((size_t)4 * HID * 4);
    float* wlast  = (float*)alloc((size_t)4 * HID * 4);
    f16*   hA     = (f16*)alloc(SLOT * 2);
    f16*   hB     = (f16*)alloc(SLOT * 2);
    float* cbuf   = (float*)alloc(SLOT * 4);
    f16*   xseq   = (f16*)alloc((size_t)T_ENC * B_SZ * TEMPD * 2);   // 88 MB
    f16*   hist   = (f16*)alloc((size_t)M_DEC * SLOT * 2);           // 192 MB
    unsigned* bar = (unsigned*)alloc(4096);

    hipMemsetAsync(hA,   0, SLOT * 2, stream);
    hipMemsetAsync(cbuf, 0, SLOT * 4, stream);
    hipMemsetAsync(bar,  0, 4096, stream);

    prep_xseq<<<(B_SZ * T_ENC * TEMPD / 4 + 255) / 256, 256, 0, stream>>>(temp_seq, xseq);
    prep_misc<<<8192, 256, 0, stream>>>(
        enc_Wih, enc_Whh, dec_Wih, dec_Whh,
        enc_bih, enc_bhh, dec_bih, dec_bhh, fc_W,
        Wenc, Wdec0, fcWh, enc_b, dec_b, wlast);
    prep_fold<<<256, 256, 0, stream>>>(
        dec_Wih, dec_Whh, dec_bih, dec_bhh, fc_W, fc_b, WdecF, biasF);
    prep_tileW<<<(32 * 18 * 16 * 64 + 255) / 256, 256, 0, stream>>>(Wenc,  WencT,  18, TEMPD + HID);
    prep_tileW<<<(32 * 18 * 16 * 64 + 255) / 256, 256, 0, stream>>>(Wdec0, Wdec0T, 18, TEMPD + HID);
    prep_tileW<<<(32 * 16 * 16 * 64 + 255) / 256, 256, 0, stream>>>(WdecF, WdecFT, 16, HID);

    PK pk;
    pk.xseq = xseq; pk.hA = hA; pk.hB = hB; pk.c = cbuf;
    pk.WencT = WencT; pk.Wdec0T = Wdec0T; pk.WdecFT = WdecFT;
    pk.enc_b = enc_b; pk.dec_b = dec_b; pk.biasF = biasF;
    pk.wlast = wlast; pk.speeds = avg_speeds;
    pk.hist = hist; pk.fcWh = fcWh; pk.fcb = fc_b; pk.out = out;
    pk.bar = bar;

    persist<<<dim3(NBLK), dim3(256), 0, stream>>>(pk);
}

// Round 12
// 9450.151 us; speedup vs baseline: 2.2380x; 2.2380x over previous
//
#include <hip/hip_runtime.h>
#include <stdint.h>

#define B_SZ   2048
#define T_ENC  168
#define TEMPD  128
#define HID    1024
#define M_DEC  48
#define NBLK   512

typedef _Float16 f16;
typedef _Float16 half8 __attribute__((ext_vector_type(8)));
typedef float    f32x4 __attribute__((ext_vector_type(4)));

__device__ __forceinline__ float sigf(float x)   { return 1.0f / (1.0f + __expf(-x)); }
__device__ __forceinline__ float tanhf_(float x) { return 2.0f / (1.0f + __expf(-2.0f * x)) - 1.0f; }

// Direct global->LDS, 16B per lane. AUX: 0 = cached; 1 = sc0 (L1-bypass, L2-coherent).
template <int AUX>
__device__ __forceinline__ void gld16(const void* g, void* l) {
    __builtin_amdgcn_global_load_lds(
        (const __attribute__((address_space(1))) void*)g,
        (__attribute__((address_space(3))) void*)l, 16, 0, AUX);
}

// 2-byte store with sc0: through L1 to the XCD's L2 (cluster coherence point).
__device__ __forceinline__ void store_h16(f16* p, f16 v) {
    union { f16 h; unsigned short u; } cv; cv.h = v;
    unsigned v32 = cv.u;
    asm volatile("global_store_short %0, %1, off sc0" :: "v"(p), "v"(v32) : "memory");
}

// ---------------------------------------------------------------------------
// prep_xseq: temp_seq [B][T][128] fp32 -> xseq [T][B][128] f16
// ---------------------------------------------------------------------------
__global__ void prep_xseq(const float* __restrict__ temp_seq, f16* __restrict__ xseq)
{
    size_t i4 = ((size_t)blockIdx.x * blockDim.x + threadIdx.x) * 4;
    size_t b  = i4 / (T_ENC * TEMPD);
    size_t r  = i4 - b * (T_ENC * TEMPD);
    size_t t  = r >> 7;
    size_t d  = r & 127;
    float4 v = *(const float4*)(temp_seq + i4);
    f16* o = xseq + ((t * B_SZ) + b) * TEMPD + d;
    o[0] = (f16)v.x; o[1] = (f16)v.y; o[2] = (f16)v.z; o[3] = (f16)v.w;
}

// ---------------------------------------------------------------------------
// prep_misc: merged f16 weights [4H][128+1024], fcW f16, biases, wlast
// ---------------------------------------------------------------------------
__global__ void prep_misc(
    const float* __restrict__ encWih, const float* __restrict__ encWhh,
    const float* __restrict__ decWih, const float* __restrict__ decWhh,
    const float* __restrict__ encbih, const float* __restrict__ encbhh,
    const float* __restrict__ decbih, const float* __restrict__ decbhh,
    const float* __restrict__ fcW,
    f16* __restrict__ Wenc, f16* __restrict__ Wdec0, f16* __restrict__ fcWh,
    float* __restrict__ enc_b, float* __restrict__ dec_b, float* __restrict__ wlast)
{
    const int NW = 4 * HID * (TEMPD + HID);
    for (int idx = blockIdx.x * blockDim.x + threadIdx.x; idx < NW;
         idx += gridDim.x * blockDim.x) {
        int j = idx / (TEMPD + HID);
        int k = idx - j * (TEMPD + HID);
        Wenc[idx]  = (f16)(k < TEMPD ? encWih[j * TEMPD + k]
                                     : encWhh[(size_t)j * HID + (k - TEMPD)]);
        Wdec0[idx] = (f16)(k < TEMPD ? decWih[j * (TEMPD + 1) + k]
                                     : decWhh[(size_t)j * HID + (k - TEMPD)]);
        if (idx < TEMPD * HID) fcWh[idx] = (f16)fcW[idx];
        if (idx < 4 * HID) {
            enc_b[idx] = encbih[idx] + encbhh[idx];
            dec_b[idx] = decbih[idx] + decbhh[idx];
            wlast[idx] = decWih[idx * (TEMPD + 1) + TEMPD];
        }
    }
}

// ---------------------------------------------------------------------------
// prep_fold: WdecF = decWhh + decWih_x @ fcW ; biasF = decb + decWih_x @ fcb
// ---------------------------------------------------------------------------
__global__ __launch_bounds__(256)
void prep_fold(
    const float* __restrict__ decWih, const float* __restrict__ decWhh,
    const float* __restrict__ decbih, const float* __restrict__ decbhh,
    const float* __restrict__ fcW,    const float* __restrict__ fcb,
    f16* __restrict__ WdecF, float* __restrict__ biasF)
{
    __shared__ float wih[16][TEMPD];
    __shared__ float fcbL[TEMPD];
    const int tid = threadIdx.x;
    const int j0  = blockIdx.x * 16;
    for (int i = tid; i < 16 * TEMPD; i += 256) {
        int r = i >> 7, p = i & 127;
        wih[r][p] = decWih[(size_t)(j0 + r) * (TEMPD + 1) + p];
    }
    if (tid < TEMPD) fcbL[tid] = fcb[tid];
    __syncthreads();
    for (int kk = 0; kk < 4; ++kk) {
        int k = kk * 256 + tid;
        float acc[16];
        #pragma unroll
        for (int r = 0; r < 16; ++r) acc[r] = decWhh[(size_t)(j0 + r) * HID + k];
        for (int p = 0; p < TEMPD; ++p) {
            float w = fcW[(size_t)p * HID + k];
            #pragma unroll
            for (int r = 0; r < 16; ++r) acc[r] += wih[r][p] * w;
        }
        #pragma unroll
        for (int r = 0; r < 16; ++r) WdecF[(size_t)(j0 + r) * HID + k] = (f16)acc[r];
    }
    if (tid < 16) {
        float b = decbih[j0 + tid] + decbhh[j0 + tid];
        for (int p = 0; p < TEMPD; ++p) b += wih[tid][p] * fcbL[p];
        biasF[j0 + tid] = b;
    }
}

// ---------------------------------------------------------------------------
// prep_tileW: merged W [4096][WS] -> fragment-ordered tiles.
// Frag flat index F = bn*NKC*16 + kc*16 + s*8 + g*2 + wc; half8 addr = F*64+lane.
// ---------------------------------------------------------------------------
__global__ void prep_tileW(const f16* __restrict__ Wsrc, f16* __restrict__ Wt,
                           int NKC, int WS)
{
    int idx = blockIdx.x * blockDim.x + threadIdx.x;
    int total = 32 * NKC * 16 * 64;
    if (idx >= total) return;
    int lane = idx & 63;
    int f    = idx >> 6;
    int wc   = f & 1;
    int g    = (f >> 1) & 3;
    int s    = (f >> 3) & 1;
    int kc   = (f >> 4) % NKC;
    int bn   = (f >> 4) / NKC;
    int row  = g * HID + bn * 32 + wc * 16 + (lane & 15);
    int k0   = kc * 64 + s * 32 + (lane >> 4) * 8;
    *(half8*)(Wt + (size_t)idx * 8) = *(const half8*)(Wsrc + (size_t)row * WS + k0);
}

// ---------------------------------------------------------------------------
// Persistent kernel, batch-partitioned across XCDs.
// Cluster (id&7) = XCD, owns batch rows [xcd*256, xcd*256+256): h/c/x/hist are
// cluster-local (L2-coherent via sc0 loads/stores). No cross-cluster traffic;
// per-cluster barrier (64 blocks). W (all 32 bn panels) streams from IF$.
// Step body = r10's verified named-wfA/wfB structure.
// ---------------------------------------------------------------------------
struct PK {
    const f16* xseq; f16* hA; f16* hB; float* c;
    const f16* WencT; const f16* Wdec0T; const f16* WdecFT;
    const float* enc_b; const float* dec_b; const float* biasF;
    const float* wlast; const float* speeds;
    f16* hist; const f16* fcWh; const float* fcb; float* out;
    unsigned* bar;   // per cluster: cnt at [c*64], gen at [c*64+32]
};

__device__ __forceinline__ void clusterbar(unsigned* bar, int xcd, unsigned target)
{
    __syncthreads();   // drains vmcnt(0) per wave -> sc0 h-stores are in L2
    if (threadIdx.x == 0) {
        unsigned* cnt = &bar[xcd * 64];
        unsigned* gen = &bar[xcd * 64 + 32];
        unsigned a = __hip_atomic_fetch_add(cnt, 1u,
                        __ATOMIC_RELAXED, __HIP_MEMORY_SCOPE_AGENT);
        if (a + 1 == 64u * target)                 // last of this cluster's 64
            __hip_atomic_store(gen, target,
                __ATOMIC_RELAXED, __HIP_MEMORY_SCOPE_AGENT);
        long spin = 0;
        while (__hip_atomic_load(gen, __ATOMIC_RELAXED,
                                 __HIP_MEMORY_SCOPE_AGENT) < target) {
            __builtin_amdgcn_s_sleep(1);
            if (++spin > 400000) break;            // fail loud, never hang
        }
        asm volatile("" ::: "memory");
    }
    __syncthreads();
}

template <int NKC, int FULLK, int DEC>
__device__ __forceinline__ void lstm_step_body(
    const f16* __restrict__ xsrc, const f16* __restrict__ hin,
    f16* __restrict__ hout, float* __restrict__ c,
    const f16* __restrict__ Wt, const float* __restrict__ bias,
    const float* __restrict__ wlast, const float* __restrict__ speeds,
    int m, int bm, int bn, half8* smem)
{
    const int tid  = threadIdx.x;
    const int lane = tid & 63;
    const int wid  = tid >> 6;
    const int wr   = wid >> 1;
    const int wc   = wid & 1;

    const half8* wtb = (const half8*)Wt + (size_t)bn * NKC * 16 * 64 + wc * 64 + lane;

    f32x4 acc[4][4];
    #pragma unroll
    for (int g = 0; g < 4; ++g)
        #pragma unroll
        for (int mr = 0; mr < 4; ++mr)
            acc[g][mr] = (f32x4){0.f, 0.f, 0.f, 0.f};

    auto stageA = [&](int slot, int kc) {
        if (FULLK && kc < 2) {
            #pragma unroll
            for (int it = 0; it < 4; ++it) {
                int pc = wid * 256 + it * 64 + lane;
                int row = pc >> 3, s = pc & 7;
                gld16<0>(xsrc + (size_t)(bm * 128 + row) * TEMPD + kc * 64 + ((s ^ (row & 7)) << 3),
                         &smem[slot * 1024 + wid * 256 + it * 64]);
            }
        } else {
            const int k0 = kc * 64 - (FULLK ? TEMPD : 0);
            #pragma unroll
            for (int it = 0; it < 4; ++it) {
                int pc = wid * 256 + it * 64 + lane;
                int row = pc >> 3, s = pc & 7;
                // h: sc0 -> L1 bypass, served by this XCD's L2 (cluster-local)
                gld16<1>(hin + (size_t)(bm * 128 + row) * HID + k0 + ((s ^ (row & 7)) << 3),
                         &smem[slot * 1024 + wid * 256 + it * 64]);
            }
        }
    };
    auto loadW = [&](half8 (&wf)[8], int kc) {
        const half8* pw = wtb + (size_t)kc * (16 * 64);
        #pragma unroll
        for (int f = 0; f < 8; ++f) wf[f] = pw[f * 128];   // f = s*4+g
    };
    auto compute = [&](int slot, const half8 (&wf)[8]) {
        #pragma unroll
        for (int s = 0; s < 2; ++s) {
            const int ks = s * 4 + (lane >> 4);
            half8 af[4];
            #pragma unroll
            for (int mr = 0; mr < 4; ++mr) {
                int row = wr * 64 + mr * 16 + (lane & 15);
                af[mr] = smem[slot * 1024 + row * 8 + (ks ^ (row & 7))];
            }
            __builtin_amdgcn_s_setprio(1);
            #pragma unroll
            for (int g = 0; g < 4; ++g)
                #pragma unroll
                for (int mr = 0; mr < 4; ++mr)
                    acc[g][mr] = __builtin_amdgcn_mfma_f32_16x16x32_f16(
                        af[mr], wf[s * 4 + g], acc[g][mr], 0, 0, 0);
            __builtin_amdgcn_s_setprio(0);
        }
    };

    half8 wfA[8], wfB[8];             // named double buffers (static indexing)
    stageA(0, 0); loadW(wfA, 0);
    __syncthreads();

    for (int kc = 0; kc < NKC; kc += 2) {          // NKC even (18 or 16)
        stageA(1, kc + 1); loadW(wfB, kc + 1);
        compute(0, wfA);
        __syncthreads();
        if (kc + 2 < NKC) { stageA(0, kc + 2); loadW(wfA, kc + 2); }
        compute(1, wfB);
        __syncthreads();
    }

    // ---- epilogue: LSTM pointwise; h stored via sc0 (L2), c cached ----
    const int col_g = bn * 32 + wc * 16 + (lane & 15);
    const float bi  = bias[col_g];
    const float bf_ = bias[HID + col_g];
    const float bg  = bias[2 * HID + col_g];
    const float bo  = bias[3 * HID + col_g];
    float wli = 0.f, wlf = 0.f, wlg = 0.f, wlo = 0.f;
    if (DEC) {
        wli = wlast[col_g];
        wlf = wlast[HID + col_g];
        wlg = wlast[2 * HID + col_g];
        wlo = wlast[3 * HID + col_g];
    }
    #pragma unroll
    for (int mr = 0; mr < 4; ++mr) {
        #pragma unroll
        for (int q = 0; q < 4; ++q) {
            int row_g = bm * 128 + wr * 64 + mr * 16 + (lane >> 4) * 4 + q;
            float pi = acc[0][mr][q] + bi;
            float pf2 = acc[1][mr][q] + bf_;
            float pg = acc[2][mr][q] + bg;
            float po = acc[3][mr][q] + bo;
            if (DEC) {
                float sp = speeds[(size_t)row_g * M_DEC + m];
                pi += sp * wli; pf2 += sp * wlf; pg += sp * wlg; po += sp * wlo;
            }
            float ii = sigf(pi), ff = sigf(pf2), gg = tanhf_(pg), oo = sigf(po);
            size_t idx = (size_t)row_g * HID + col_g;
            float cn = ff * c[idx] + ii * gg;
            c[idx] = cn;
            store_h16(hout + idx, (f16)(oo * tanhf_(cn)));
        }
    }
}

__global__ __launch_bounds__(256, 2)
void persist(PK p)
{
    __shared__ half8 smem[2048];   // 32 KB: 2 x 16 KB A slots; fc reuses [0,1280)

    const size_t SLOT = (size_t)B_SZ * HID;
    const int tid  = threadIdx.x;
    const int lane = tid & 63;
    const int wid  = tid >> 6;
    const int wr   = wid >> 1;
    const int wc   = wid & 1;
    const int id   = blockIdx.x;
    const int xcd  = id & 7;          // cluster = XCD (round-robin dispatch, m09)
    const int rank = id >> 3;         // 0..63 within cluster
    const int bm   = xcd * 2 + (rank & 1);   // cluster owns rows [xcd*256, +256)
    const int bn   = rank >> 1;       // 0..31 (full hidden range per cluster)

    for (int step = 0; step < T_ENC + M_DEC; ++step) {
        const int m = step - T_ENC;
        if (step < T_ENC) {
            const f16* xsrc = p.xseq + (size_t)step * (B_SZ * TEMPD);
            const f16* hin  = (step & 1) ? p.hB : p.hA;
            f16* hout       = (step & 1) ? p.hA : p.hB;
            lstm_step_body<18, 1, 0>(xsrc, hin, hout, p.c, p.WencT, p.enc_b,
                                     nullptr, nullptr, 0, bm, bn, smem);
        } else if (m == 0) {
            const f16* xsrc = p.xseq + (size_t)(T_ENC - 1) * (B_SZ * TEMPD);
            lstm_step_body<18, 1, 1>(xsrc, p.hA, p.hist, p.c, p.Wdec0T, p.dec_b,
                                     p.wlast, p.speeds, 0, bm, bn, smem);
        } else {
            const f16* hin = p.hist + (size_t)(m - 1) * SLOT;
            f16* hout      = p.hist + (size_t)m * SLOT;
            lstm_step_body<16, 0, 1>(nullptr, hin, hout, p.c, p.WdecFT, p.biasF,
                                     p.wlast, p.speeds, m, bm, bn, smem);
        }
        clusterbar(p.bar, xcd, (unsigned)(step + 1));
    }

    // ---- fc phase (cluster-local rows): preds = hist @ fcW^T + fcb ----
    // Per cluster: 48 slots x 8 row-tiles(32) = 384 tiles over 64 blocks.
    for (int g = rank; g < M_DEC * 8; g += 64) {
        const int slot = g >> 3;
        const int b0   = xcd * 256 + (g & 7) * 32;
        const f16* hrow = p.hist + (size_t)slot * SLOT + (size_t)b0 * HID;

        f32x4 facc[4];
        #pragma unroll
        for (int nr = 0; nr < 4; ++nr) facc[nr] = (f32x4){0.f, 0.f, 0.f, 0.f};

        for (int kc = 0; kc < HID / 64; ++kc) {
            const int k0 = kc * 64;
            {
                int row = tid >> 3, s = tid & 7;
                gld16<1>(hrow + (size_t)row * HID + k0 + ((s ^ (row & 7)) << 3), &smem[wid * 64]);
            }
            #pragma unroll
            for (int it = 0; it < 4; ++it) {
                int pc = wid * 256 + it * 64 + lane;
                int row = pc >> 3, s = pc & 7;
                gld16<0>(p.fcWh + (size_t)row * HID + k0 + ((s ^ (row & 7)) << 3),
                         &smem[256 + wid * 256 + it * 64]);
            }
            __syncthreads();
            #pragma unroll
            for (int s2 = 0; s2 < 2; ++s2) {
                int arow = wr * 16 + (lane & 15);
                int ks = s2 * 4 + (lane >> 4);
                half8 a = smem[arow * 8 + (ks ^ (arow & 7))];
                #pragma unroll
                for (int nr = 0; nr < 4; ++nr) {
                    int brow = wc * 64 + nr * 16 + (lane & 15);
                    half8 bfr = smem[256 + brow * 8 + (ks ^ (brow & 7))];
                    facc[nr] = __builtin_amdgcn_mfma_f32_16x16x32_f16(a, bfr, facc[nr], 0, 0, 0);
                }
            }
            __syncthreads();
        }
        #pragma unroll
        for (int nr = 0; nr < 4; ++nr)
            #pragma unroll
            for (int q = 0; q < 4; ++q) {
                int rloc = wr * 16 + (lane >> 4) * 4 + q;
                int col  = wc * 64 + nr * 16 + (lane & 15);
                p.out[(size_t)(b0 + rloc) * (M_DEC * TEMPD) + (size_t)slot * TEMPD + col]
                    = facc[nr][q] + p.fcb[col];
            }
    }
}

// ---------------------------------------------------------------------------
extern "C" void kernel_launch(void* const* d_in, const int* in_sizes, int n_in,
                              void* d_out, int out_size, void* d_ws, size_t ws_size,
                              hipStream_t stream)
{
    (void)in_sizes; (void)n_in; (void)out_size; (void)ws_size;
    const float* temp_seq   = (const float*)d_in[0];
    const float* avg_speeds = (const float*)d_in[1];
    const float* enc_Wih    = (const float*)d_in[2];
    const float* enc_Whh    = (const float*)d_in[3];
    const float* enc_bih    = (const float*)d_in[4];
    const float* enc_bhh    = (const float*)d_in[5];
    const float* dec_Wih    = (const float*)d_in[6];
    const float* dec_Whh    = (const float*)d_in[7];
    const float* dec_bih    = (const float*)d_in[8];
    const float* dec_bhh    = (const float*)d_in[9];
    const float* fc_W       = (const float*)d_in[10];
    const float* fc_b       = (const float*)d_in[11];
    float* out = (float*)d_out;

    char* ws = (char*)d_ws;
    size_t off = 0;
    auto alloc = [&](size_t bytes) -> void* {
        void* p = ws + off;
        off += (bytes + 255) & ~(size_t)255;
        return p;
    };
    const size_t SLOT = (size_t)B_SZ * HID;
    f16*   Wenc   = (f16*)alloc((size_t)4 * HID * (TEMPD + HID) * 2);
    f16*   Wdec0  = (f16*)alloc((size_t)4 * HID * (TEMPD + HID) * 2);
    f16*   WdecF  = (f16*)alloc((size_t)4 * HID * HID * 2);
    f16*   WencT  = (f16*)alloc((size_t)32 * 18 * 16 * 64 * 8 * 2);
    f16*   Wdec0T = (f16*)alloc((size_t)32 * 18 * 16 * 64 * 8 * 2);
    f16*   WdecFT = (f16*)alloc((size_t)32 * 16 * 16 * 64 * 8 * 2);
    f16*   fcWh   = (f16*)alloc((size_t)TEMPD * HID * 2);
    float* enc_b  = (float*)alloc((size_t)4 * HID * 4);
    float* dec_b  = (float*)alloc((size_t)4 * HID * 4);
    float* biasF  = (float*)alloc((size_t)4 * HID * 4);
    float* wlast  = (float*)alloc((size_t)4 * HID * 4);
    f16*   hA     = (f16*)alloc(SLOT * 2);
    f16*   hB     = (f16*)alloc(SLOT * 2);
    float* cbuf   = (float*)alloc(SLOT * 4);
    f16*   xseq   = (f16*)alloc((size_t)T_ENC * B_SZ * TEMPD * 2);   // 88 MB
    f16*   hist   = (f16*)alloc((size_t)M_DEC * SLOT * 2);           // 192 MB
    unsigned* bar = (unsigned*)alloc(4096);   // cluster c: cnt [c*64], gen [c*64+32]

    hipMemsetAsync(hA,   0, SLOT * 2, stream);
    hipMemsetAsync(cbuf, 0, SLOT * 4, stream);
    hipMemsetAsync(bar,  0, 4096, stream);

    prep_xseq<<<(B_SZ * T_ENC * TEMPD / 4 + 255) / 256, 256, 0, stream>>>(temp_seq, xseq);
    prep_misc<<<8192, 256, 0, stream>>>(
        enc_Wih, enc_Whh, dec_Wih, dec_Whh,
        enc_bih, enc_bhh, dec_bih, dec_bhh, fc_W,
        Wenc, Wdec0, fcWh, enc_b, dec_b, wlast);
    prep_fold<<<256, 256, 0, stream>>>(
        dec_Wih, dec_Whh, dec_bih, dec_bhh, fc_W, fc_b, WdecF, biasF);
    prep_tileW<<<(32 * 18 * 16 * 64 + 255) / 256, 256, 0, stream>>>(Wenc,  WencT,  18, TEMPD + HID);
    prep_tileW<<<(32 * 18 * 16 * 64 + 255) / 256, 256, 0, stream>>>(Wdec0, Wdec0T, 18, TEMPD + HID);
    prep_tileW<<<(32 * 16 * 16 * 64 + 255) / 256, 256, 0, stream>>>(WdecF, WdecFT, 16, HID);

    PK pk;
    pk.xseq = xseq; pk.hA = hA; pk.hB = hB; pk.c = cbuf;
    pk.WencT = WencT; pk.Wdec0T = Wdec0T; pk.WdecFT = WdecFT;
    pk.enc_b = enc_b; pk.dec_b = dec_b; pk.biasF = biasF;
    pk.wlast = wlast; pk.speeds = avg_speeds;
    pk.hist = hist; pk.fcWh = fcWh; pk.fcb = fc_b; pk.out = out;
    pk.bar = bar;

    persist<<<dim3(NBLK), dim3(256), 0, stream>>>(pk);
}

// Round 13
// 9215.751 us; speedup vs baseline: 2.2949x; 1.0254x over previous
//
#include <hip/hip_runtime.h>
#include <stdint.h>

#define B_SZ   2048
#define T_ENC  168
#define TEMPD  128
#define HID    1024
#define M_DEC  48
#define NBLK   512

typedef _Float16 f16;
typedef _Float16 half8 __attribute__((ext_vector_type(8)));
typedef float    f32x4 __attribute__((ext_vector_type(4)));

__device__ __forceinline__ float sigf(float x)   { return 1.0f / (1.0f + __expf(-x)); }
__device__ __forceinline__ float tanhf_(float x) { return 2.0f / (1.0f + __expf(-2.0f * x)) - 1.0f; }

// Direct global->LDS, 16B per lane. AUX: 0 = cached; 17 = sc0|sc1 coherent path.
template <int AUX>
__device__ __forceinline__ void gld16(const void* g, void* l) {
    __builtin_amdgcn_global_load_lds(
        (const __attribute__((address_space(1))) void*)g,
        (__attribute__((address_space(3))) void*)l, 16, 0, AUX);
}

// 2-byte store with sc0 sc1: write-through to coherent point (IF$).
__device__ __forceinline__ void store_h16(f16* p, f16 v) {
    union { f16 h; unsigned short u; } cv; cv.h = v;
    unsigned v32 = cv.u;
    asm volatile("global_store_short %0, %1, off sc0 sc1" :: "v"(p), "v"(v32) : "memory");
}

#define WAITV16() asm volatile("s_waitcnt vmcnt(16)" ::: "memory")
#define SBAR()    do { __builtin_amdgcn_sched_barrier(0); \
                       __builtin_amdgcn_s_barrier();      \
                       __builtin_amdgcn_sched_barrier(0); } while (0)

// ---------------------------------------------------------------------------
// prep_xseq: temp_seq [B][T][128] fp32 -> xseq [T][B][128] f16
// ---------------------------------------------------------------------------
__global__ void prep_xseq(const float* __restrict__ temp_seq, f16* __restrict__ xseq)
{
    size_t i4 = ((size_t)blockIdx.x * blockDim.x + threadIdx.x) * 4;
    size_t b  = i4 / (T_ENC * TEMPD);
    size_t r  = i4 - b * (T_ENC * TEMPD);
    size_t t  = r >> 7;
    size_t d  = r & 127;
    float4 v = *(const float4*)(temp_seq + i4);
    f16* o = xseq + ((t * B_SZ) + b) * TEMPD + d;
    o[0] = (f16)v.x; o[1] = (f16)v.y; o[2] = (f16)v.z; o[3] = (f16)v.w;
}

// ---------------------------------------------------------------------------
// prep_misc: merged f16 weights [4H][128+1024], fcW f16, biases, wlast
// ---------------------------------------------------------------------------
__global__ void prep_misc(
    const float* __restrict__ encWih, const float* __restrict__ encWhh,
    const float* __restrict__ decWih, const float* __restrict__ decWhh,
    const float* __restrict__ encbih, const float* __restrict__ encbhh,
    const float* __restrict__ decbih, const float* __restrict__ decbhh,
    const float* __restrict__ fcW,
    f16* __restrict__ Wenc, f16* __restrict__ Wdec0, f16* __restrict__ fcWh,
    float* __restrict__ enc_b, float* __restrict__ dec_b, float* __restrict__ wlast)
{
    const int NW = 4 * HID * (TEMPD + HID);
    for (int idx = blockIdx.x * blockDim.x + threadIdx.x; idx < NW;
         idx += gridDim.x * blockDim.x) {
        int j = idx / (TEMPD + HID);
        int k = idx - j * (TEMPD + HID);
        Wenc[idx]  = (f16)(k < TEMPD ? encWih[j * TEMPD + k]
                                     : encWhh[(size_t)j * HID + (k - TEMPD)]);
        Wdec0[idx] = (f16)(k < TEMPD ? decWih[j * (TEMPD + 1) + k]
                                     : decWhh[(size_t)j * HID + (k - TEMPD)]);
        if (idx < TEMPD * HID) fcWh[idx] = (f16)fcW[idx];
        if (idx < 4 * HID) {
            enc_b[idx] = encbih[idx] + encbhh[idx];
            dec_b[idx] = decbih[idx] + decbhh[idx];
            wlast[idx] = decWih[idx * (TEMPD + 1) + TEMPD];
        }
    }
}

// ---------------------------------------------------------------------------
// prep_fold: WdecF = decWhh + decWih_x @ fcW ; biasF = decb + decWih_x @ fcb
// ---------------------------------------------------------------------------
__global__ __launch_bounds__(256)
void prep_fold(
    const float* __restrict__ decWih, const float* __restrict__ decWhh,
    const float* __restrict__ decbih, const float* __restrict__ decbhh,
    const float* __restrict__ fcW,    const float* __restrict__ fcb,
    f16* __restrict__ WdecF, float* __restrict__ biasF)
{
    __shared__ float wih[16][TEMPD];
    __shared__ float fcbL[TEMPD];
    const int tid = threadIdx.x;
    const int j0  = blockIdx.x * 16;
    for (int i = tid; i < 16 * TEMPD; i += 256) {
        int r = i >> 7, p = i & 127;
        wih[r][p] = decWih[(size_t)(j0 + r) * (TEMPD + 1) + p];
    }
    if (tid < TEMPD) fcbL[tid] = fcb[tid];
    __syncthreads();
    for (int kk = 0; kk < 4; ++kk) {
        int k = kk * 256 + tid;
        float acc[16];
        #pragma unroll
        for (int r = 0; r < 16; ++r) acc[r] = decWhh[(size_t)(j0 + r) * HID + k];
        for (int p = 0; p < TEMPD; ++p) {
            float w = fcW[(size_t)p * HID + k];
            #pragma unroll
            for (int r = 0; r < 16; ++r) acc[r] += wih[r][p] * w;
        }
        #pragma unroll
        for (int r = 0; r < 16; ++r) WdecF[(size_t)(j0 + r) * HID + k] = (f16)acc[r];
    }
    if (tid < 16) {
        float b = decbih[j0 + tid] + decbhh[j0 + tid];
        for (int p = 0; p < TEMPD; ++p) b += wih[tid][p] * fcbL[p];
        biasF[j0 + tid] = b;
    }
}

// ---------------------------------------------------------------------------
// prep_tileW: merged W [4096][WS] -> fragment-ordered tiles.
// Frag flat index F = bn*NKC*16 + kc*16 + s*8 + g*2 + wc; half8 addr = F*64+lane.
// ---------------------------------------------------------------------------
__global__ void prep_tileW(const f16* __restrict__ Wsrc, f16* __restrict__ Wt,
                           int NKC, int WS)
{
    int idx = blockIdx.x * blockDim.x + threadIdx.x;
    int total = 32 * NKC * 16 * 64;
    if (idx >= total) return;
    int lane = idx & 63;
    int f    = idx >> 6;
    int wc   = f & 1;
    int g    = (f >> 1) & 3;
    int s    = (f >> 3) & 1;
    int kc   = (f >> 4) % NKC;
    int bn   = (f >> 4) / NKC;
    int row  = g * HID + bn * 32 + wc * 16 + (lane & 15);
    int k0   = kc * 64 + s * 32 + (lane >> 4) * 8;
    *(half8*)(Wt + (size_t)idx * 8) = *(const half8*)(Wsrc + (size_t)row * WS + k0);
}

// ---------------------------------------------------------------------------
// Persistent kernel, N-partitioned (r10 layout). Fix vs r10: kc-loop uses
// counted vmcnt(16) + raw s_barrier instead of __syncthreads (which drained
// vmcnt to 0 and killed the pipeline). A: 4-slot LDS pipeline (slot = kc&3,
// LDS addressing not register indexing). W: named wfA/wfB (no scratch).
// Queue invariant after each drain: [A(k+1) 4, W(k+1) 8, A(k+2) 4] = 16.
// ---------------------------------------------------------------------------
struct PK {
    const f16* xseq; f16* hA; f16* hB; float* c;
    const f16* WencT; const f16* Wdec0T; const f16* WdecFT;
    const float* enc_b; const float* dec_b; const float* biasF;
    const float* wlast; const float* speeds;
    f16* hist; const f16* fcWh; const float* fcb; float* out;
    unsigned* bar;   // [0..7]*32: per-XCD cnt lines; [256]: gcnt; [288]: gen
};

__device__ __forceinline__ void gridbar(unsigned* bar, int xcd, unsigned target)
{
    __syncthreads();   // drains vmcnt(0) per wave -> h sc-stores visible
    if (threadIdx.x == 0) {
        unsigned a = __hip_atomic_fetch_add(&bar[xcd * 32], 1u,
                        __ATOMIC_RELAXED, __HIP_MEMORY_SCOPE_AGENT);
        if (((a + 1) & 63) == 0) {
            unsigned b = __hip_atomic_fetch_add(&bar[256], 1u,
                            __ATOMIC_RELAXED, __HIP_MEMORY_SCOPE_AGENT);
            if (((b + 1) & 7) == 0)
                __hip_atomic_store(&bar[288], target,
                    __ATOMIC_RELAXED, __HIP_MEMORY_SCOPE_AGENT);
        }
        long spin = 0;
        while (__hip_atomic_load(&bar[288], __ATOMIC_RELAXED,
                                 __HIP_MEMORY_SCOPE_AGENT) < target) {
            __builtin_amdgcn_s_sleep(1);
            if (++spin > 400000) break;            // fail loud, never hang
        }
        asm volatile("" ::: "memory");
    }
    __syncthreads();
}

template <int NKC, int FULLK, int DEC>
__device__ __forceinline__ void lstm_step_body(
    const f16* __restrict__ xsrc, const f16* __restrict__ hin,
    f16* __restrict__ hout, float* __restrict__ c,
    const f16* __restrict__ Wt, const float* __restrict__ bias,
    const float* __restrict__ wlast, const float* __restrict__ speeds,
    int m, int bm, int bn, half8* smem)
{
    const int tid  = threadIdx.x;
    const int lane = tid & 63;
    const int wid  = tid >> 6;
    const int wr   = wid >> 1;
    const int wc   = wid & 1;

    const half8* wtb = (const half8*)Wt + (size_t)bn * NKC * 16 * 64 + wc * 64 + lane;

    f32x4 acc[4][4];
    #pragma unroll
    for (int g = 0; g < 4; ++g)
        #pragma unroll
        for (int mr = 0; mr < 4; ++mr)
            acc[g][mr] = (f32x4){0.f, 0.f, 0.f, 0.f};

    auto stageA = [&](int slot, int kc) {
        if (FULLK && kc < 2) {
            #pragma unroll
            for (int it = 0; it < 4; ++it) {
                int pc = wid * 256 + it * 64 + lane;
                int row = pc >> 3, s = pc & 7;
                gld16<0>(xsrc + (size_t)(bm * 128 + row) * TEMPD + kc * 64 + ((s ^ (row & 7)) << 3),
                         &smem[slot * 1024 + wid * 256 + it * 64]);
            }
        } else {
            const int k0 = kc * 64 - (FULLK ? TEMPD : 0);
            #pragma unroll
            for (int it = 0; it < 4; ++it) {
                int pc = wid * 256 + it * 64 + lane;
                int row = pc >> 3, s = pc & 7;
                // h: sc0|sc1 -> coherent IF$ read
                gld16<17>(hin + (size_t)(bm * 128 + row) * HID + k0 + ((s ^ (row & 7)) << 3),
                          &smem[slot * 1024 + wid * 256 + it * 64]);
            }
        }
    };
    auto loadW = [&](half8 (&wf)[8], int kc) {
        const half8* pw = wtb + (size_t)kc * (16 * 64);
        #pragma unroll
        for (int f = 0; f < 8; ++f) wf[f] = pw[f * 128];   // f = s*4+g
    };
    auto compute = [&](int slot, const half8 (&wf)[8]) {
        #pragma unroll
        for (int s = 0; s < 2; ++s) {
            const int ks = s * 4 + (lane >> 4);
            half8 af[4];
            #pragma unroll
            for (int mr = 0; mr < 4; ++mr) {
                int row = wr * 64 + mr * 16 + (lane & 15);
                af[mr] = smem[slot * 1024 + row * 8 + (ks ^ (row & 7))];
            }
            __builtin_amdgcn_s_setprio(1);
            #pragma unroll
            for (int g = 0; g < 4; ++g)
                #pragma unroll
                for (int mr = 0; mr < 4; ++mr)
                    acc[g][mr] = __builtin_amdgcn_mfma_f32_16x16x32_f16(
                        af[mr], wf[s * 4 + g], acc[g][mr], 0, 0, 0);
            __builtin_amdgcn_s_setprio(0);
        }
    };

    half8 wfA[8], wfB[8];   // named double buffers (static indexing, no scratch)

    // prologue queue: A(0)4, W(0)8, A(1)4, W(1)8, A(2)4 = 28 outstanding
    stageA(0, 0); loadW(wfA, 0);
    stageA(1, 1); loadW(wfB, 1);
    stageA(2, 2);

    for (int kc = 0; kc < NKC; kc += 2) {   // NKC even (18 or 16)
        // ---- even kc: compute from slot kc&3 with wfA ----
        WAITV16();               // drains A(kc), W(kc); leaves A/W(kc+1), A(kc+2)
        SBAR();                  // A(kc) visible to all waves
        compute(kc & 3, wfA);
        loadW(wfA, (kc + 2 < NKC) ? kc + 2 : NKC - 1);       // W 2-ahead (dummy at tail)
        stageA((kc + 3) & 3, (kc + 3 < NKC) ? kc + 3 : NKC - 1);  // A 3-ahead
        // ---- odd kc+1: compute with wfB ----
        WAITV16();
        SBAR();
        compute((kc + 1) & 3, wfB);
        loadW(wfB, (kc + 3 < NKC) ? kc + 3 : NKC - 1);
        stageA((kc + 4) & 3, (kc + 4 < NKC) ? kc + 4 : NKC - 1);
    }

    // ---- epilogue: LSTM pointwise; h stored via sc0sc1 (IF$), c cached ----
    const int col_g = bn * 32 + wc * 16 + (lane & 15);
    const float bi  = bias[col_g];
    const float bf_ = bias[HID + col_g];
    const float bg  = bias[2 * HID + col_g];
    const float bo  = bias[3 * HID + col_g];
    float wli = 0.f, wlf = 0.f, wlg = 0.f, wlo = 0.f;
    if (DEC) {
        wli = wlast[col_g];
        wlf = wlast[HID + col_g];
        wlg = wlast[2 * HID + col_g];
        wlo = wlast[3 * HID + col_g];
    }
    #pragma unroll
    for (int mr = 0; mr < 4; ++mr) {
        #pragma unroll
        for (int q = 0; q < 4; ++q) {
            int row_g = bm * 128 + wr * 64 + mr * 16 + (lane >> 4) * 4 + q;
            float pi = acc[0][mr][q] + bi;
            float pf2 = acc[1][mr][q] + bf_;
            float pg = acc[2][mr][q] + bg;
            float po = acc[3][mr][q] + bo;
            if (DEC) {
                float sp = speeds[(size_t)row_g * M_DEC + m];
                pi += sp * wli; pf2 += sp * wlf; pg += sp * wlg; po += sp * wlo;
            }
            float ii = sigf(pi), ff = sigf(pf2), gg = tanhf_(pg), oo = sigf(po);
            size_t idx = (size_t)row_g * HID + col_g;
            float cn = ff * c[idx] + ii * gg;
            c[idx] = cn;
            store_h16(hout + idx, (f16)(oo * tanhf_(cn)));
        }
    }
}

__global__ __launch_bounds__(256, 2)
void persist(PK p)
{
    __shared__ half8 smem[4096];   // 64 KB: 4 x 16 KB A slots; fc reuses [0,1280)

    const size_t SLOT = (size_t)B_SZ * HID;
    const int tid  = threadIdx.x;
    const int lane = tid & 63;
    const int wid  = tid >> 6;
    const int wr   = wid >> 1;
    const int wc   = wid & 1;
    const int id   = blockIdx.x;
    const int xcd  = id & 7;
    const int swzb = xcd * 64 + (id >> 3);        // bijective XCD swizzle
    const int bn   = swzb >> 4;       // 0..31
    const int bm   = swzb & 15;       // 0..15

    for (int step = 0; step < T_ENC + M_DEC; ++step) {
        const int m = step - T_ENC;
        if (step < T_ENC) {
            const f16* xsrc = p.xseq + (size_t)step * (B_SZ * TEMPD);
            const f16* hin  = (step & 1) ? p.hB : p.hA;
            f16* hout       = (step & 1) ? p.hA : p.hB;
            lstm_step_body<18, 1, 0>(xsrc, hin, hout, p.c, p.WencT, p.enc_b,
                                     nullptr, nullptr, 0, bm, bn, smem);
        } else if (m == 0) {
            const f16* xsrc = p.xseq + (size_t)(T_ENC - 1) * (B_SZ * TEMPD);
            lstm_step_body<18, 1, 1>(xsrc, p.hA, p.hist, p.c, p.Wdec0T, p.dec_b,
                                     p.wlast, p.speeds, 0, bm, bn, smem);
        } else {
            const f16* hin = p.hist + (size_t)(m - 1) * SLOT;
            f16* hout      = p.hist + (size_t)m * SLOT;
            lstm_step_body<16, 0, 1>(nullptr, hin, hout, p.c, p.WdecFT, p.biasF,
                                     p.wlast, p.speeds, m, bm, bn, smem);
        }
        gridbar(p.bar, xcd, (unsigned)(step + 1));
    }

    // ---- fc phase: preds[slot] = hist[slot] @ fcW^T + fcb -> d_out ----
    for (int tile = id; tile < M_DEC * 64; tile += NBLK) {
        const int slot = tile >> 6;
        const int b0   = (tile & 63) * 32;
        const f16* hrow = p.hist + (size_t)slot * SLOT + (size_t)b0 * HID;

        f32x4 facc[4];
        #pragma unroll
        for (int nr = 0; nr < 4; ++nr) facc[nr] = (f32x4){0.f, 0.f, 0.f, 0.f};

        for (int kc = 0; kc < HID / 64; ++kc) {
            const int k0 = kc * 64;
            {
                int row = tid >> 3, s = tid & 7;
                gld16<0>(hrow + (size_t)row * HID + k0 + ((s ^ (row & 7)) << 3), &smem[wid * 64]);
            }
            #pragma unroll
            for (int it = 0; it < 4; ++it) {
                int pc = wid * 256 + it * 64 + lane;
                int row = pc >> 3, s = pc & 7;
                gld16<0>(p.fcWh + (size_t)row * HID + k0 + ((s ^ (row & 7)) << 3),
                         &smem[256 + wid * 256 + it * 64]);
            }
            __syncthreads();
            #pragma unroll
            for (int s2 = 0; s2 < 2; ++s2) {
                int arow = wr * 16 + (lane & 15);
                int ks = s2 * 4 + (lane >> 4);
                half8 a = smem[arow * 8 + (ks ^ (arow & 7))];
                #pragma unroll
                for (int nr = 0; nr < 4; ++nr) {
                    int brow = wc * 64 + nr * 16 + (lane & 15);
                    half8 bfr = smem[256 + brow * 8 + (ks ^ (brow & 7))];
                    facc[nr] = __builtin_amdgcn_mfma_f32_16x16x32_f16(a, bfr, facc[nr], 0, 0, 0);
                }
            }
            __syncthreads();
        }
        #pragma unroll
        for (int nr = 0; nr < 4; ++nr)
            #pragma unroll
            for (int q = 0; q < 4; ++q) {
                int rloc = wr * 16 + (lane >> 4) * 4 + q;
                int col  = wc * 64 + nr * 16 + (lane & 15);
                p.out[(size_t)(b0 + rloc) * (M_DEC * TEMPD) + (size_t)slot * TEMPD + col]
                    = facc[nr][q] + p.fcb[col];
            }
    }
}

// ---------------------------------------------------------------------------
extern "C" void kernel_launch(void* const* d_in, const int* in_sizes, int n_in,
                              void* d_out, int out_size, void* d_ws, size_t ws_size,
                              hipStream_t stream)
{
    (void)in_sizes; (void)n_in; (void)out_size; (void)ws_size;
    const float* temp_seq   = (const float*)d_in[0];
    const float* avg_speeds = (const float*)d_in[1];
    const float* enc_Wih    = (const float*)d_in[2];
    const float* enc_Whh    = (const float*)d_in[3];
    const float* enc_bih    = (const float*)d_in[4];
    const float* enc_bhh    = (const float*)d_in[5];
    const float* dec_Wih    = (const float*)d_in[6];
    const float* dec_Whh    = (const float*)d_in[7];
    const float* dec_bih    = (const float*)d_in[8];
    const float* dec_bhh    = (const float*)d_in[9];
    const float* fc_W       = (const float*)d_in[10];
    const float* fc_b       = (const float*)d_in[11];
    float* out = (float*)d_out;

    char* ws = (char*)d_ws;
    size_t off = 0;
    auto alloc = [&](size_t bytes) -> void* {
        void* p = ws + off;
        off += (bytes + 255) & ~(size_t)255;
        return p;
    };
    const size_t SLOT = (size_t)B_SZ * HID;
    f16*   Wenc   = (f16*)alloc((size_t)4 * HID * (TEMPD + HID) * 2);
    f16*   Wdec0  = (f16*)alloc((size_t)4 * HID * (TEMPD + HID) * 2);
    f16*   WdecF  = (f16*)alloc((size_t)4 * HID * HID * 2);
    f16*   WencT  = (f16*)alloc((size_t)32 * 18 * 16 * 64 * 8 * 2);
    f16*   Wdec0T = (f16*)alloc((size_t)32 * 18 * 16 * 64 * 8 * 2);
    f16*   WdecFT = (f16*)alloc((size_t)32 * 16 * 16 * 64 * 8 * 2);
    f16*   fcWh   = (f16*)alloc((size_t)TEMPD * HID * 2);
    float* enc_b  = (float*)alloc((size_t)4 * HID * 4);
    float* dec_b  = (float*)alloc((size_t)4 * HID * 4);
    float* biasF  = (float*)alloc((size_t)4 * HID * 4);
    float* wlast  = (float*)alloc((size_t)4 * HID * 4);
    f16*   hA     = (f16*)alloc(SLOT * 2);
    f16*   hB     = (f16*)alloc(SLOT * 2);
    float* cbuf   = (float*)alloc(SLOT * 4);
    f16*   xseq   = (f16*)alloc((size_t)T_ENC * B_SZ * TEMPD * 2);   // 88 MB
    f16*   hist   = (f16*)alloc((size_t)M_DEC * SLOT * 2);           // 192 MB
    unsigned* bar = (unsigned*)alloc(4096);

    hipMemsetAsync(hA,   0, SLOT * 2, stream);
    hipMemsetAsync(cbuf, 0, SLOT * 4, stream);
    hipMemsetAsync(bar,  0, 4096, stream);

    prep_xseq<<<(B_SZ * T_ENC * TEMPD / 4 + 255) / 256, 256, 0, stream>>>(temp_seq, xseq);
    prep_misc<<<8192, 256, 0, stream>>>(
        enc_Wih, enc_Whh, dec_Wih, dec_Whh,
        enc_bih, enc_bhh, dec_bih, dec_bhh, fc_W,
        Wenc, Wdec0, fcWh, enc_b, dec_b, wlast);
    prep_fold<<<256, 256, 0, stream>>>(
        dec_Wih, dec_Whh, dec_bih, dec_bhh, fc_W, fc_b, WdecF, biasF);
    prep_tileW<<<(32 * 18 * 16 * 64 + 255) / 256, 256, 0, stream>>>(Wenc,  WencT,  18, TEMPD + HID);
    prep_tileW<<<(32 * 18 * 16 * 64 + 255) / 256, 256, 0, stream>>>(Wdec0, Wdec0T, 18, TEMPD + HID);
    prep_tileW<<<(32 * 16 * 16 * 64 + 255) / 256, 256, 0, stream>>>(WdecF, WdecFT, 16, HID);

    PK pk;
    pk.xseq = xseq; pk.hA = hA; pk.hB = hB; pk.c = cbuf;
    pk.WencT = WencT; pk.Wdec0T = Wdec0T; pk.WdecFT = WdecFT;
    pk.enc_b = enc_b; pk.dec_b = dec_b; pk.biasF = biasF;
    pk.wlast = wlast; pk.speeds = avg_speeds;
    pk.hist = hist; pk.fcWh = fcWh; pk.fcb = fc_b; pk.out = out;
    pk.bar = bar;

    persist<<<dim3(NBLK), dim3(256), 0, stream>>>(pk);
}